// Round 1
// baseline (1066.592 us; speedup 1.0000x reference)
//
#include <hip/hip_runtime.h>
#include <stdint.h>

// ---------------------------------------------------------------------------
// EnhancedXLSTM on MI355X (gfx950).  Round 3:
//   - New 256x256 deep-pipelined GEMM core (ring-of-4 LDS slots, BK=32,
//     counted vmcnt(8) across raw s_barrier, XOR-swizzled LDS, setprio) for
//     xs / gates / qkv GEMMs.  Old 128^2 core kept for the final fp32 GEMM.
//   - LSTM pointwise: fast sigmoid/tanh via v_exp+v_rcp, 8 elem/thread.
//   - cvt: 8 elem/thread.
// ---------------------------------------------------------------------------

#define Bq 16384
#define Dq 512
#define Sq 3
#define Hq 8

typedef unsigned short u16;
typedef __bf16 bf16x8 __attribute__((ext_vector_type(8)));
typedef float f32x4 __attribute__((ext_vector_type(4)));
typedef u16 u16x8 __attribute__((ext_vector_type(8)));
typedef u16 u16x4v __attribute__((ext_vector_type(4)));

__device__ __forceinline__ u16 f2bf(float f) {
    union { float f; uint32_t u; } c; c.f = f;
    uint32_t u = c.u;
    return (u16)((u + 0x7fffu + ((u >> 16) & 1u)) >> 16);   // RNE
}
__device__ __forceinline__ float bf2f(u16 h) {
    union { uint32_t u; float f; } c; c.u = ((uint32_t)h) << 16;
    return c.f;
}

__device__ __forceinline__ void async16(const u16* g, u16* l) {
    __builtin_amdgcn_global_load_lds(
        (__attribute__((address_space(1))) void*)const_cast<u16*>(g),
        (__attribute__((address_space(3))) void*)l, 16, 0, 0);
}

__device__ __forceinline__ float sigf(float x) {
    return __builtin_amdgcn_rcpf(1.f + __expf(-x));
}
__device__ __forceinline__ float tanhfast(float x) {
    return 1.f - 2.f * __builtin_amdgcn_rcpf(1.f + __expf(2.f * x));
}

// ---------------------------------------------------------------------------
// Fused fp32 -> bf16 convert over up to 9 tensors, 8 elem/thread.
// (every tensor size is a multiple of 512, so an 8-span never crosses bounds)
// ---------------------------------------------------------------------------
struct CvtArgs {
    const float* src[9];
    u16* dst[9];
    long long bound[9];   // inclusive-scan element bounds (bound[8] == total)
};

__global__ __launch_bounds__(256) void cvt_all_kernel(CvtArgs a, long long total)
{
    long long i = ((long long)blockIdx.x * 256 + threadIdx.x) * 8;
    if (i >= total) return;
    const float* s = a.src[0];
    u16* d = a.dst[0];
    long long base = 0;
#pragma unroll
    for (int t = 0; t < 8; ++t) {
        if (i >= a.bound[t]) { s = a.src[t + 1]; d = a.dst[t + 1]; base = a.bound[t]; }
    }
    const long long l = i - base;
    float4 v0 = *(const float4*)(s + l);
    float4 v1 = *(const float4*)(s + l + 4);
    u16x8 o;
    o[0] = f2bf(v0.x); o[1] = f2bf(v0.y); o[2] = f2bf(v0.z); o[3] = f2bf(v0.w);
    o[4] = f2bf(v1.x); o[5] = f2bf(v1.y); o[6] = f2bf(v1.z); o[7] = f2bf(v1.w);
    *(u16x8*)(d + l) = o;
}

// ---------------------------------------------------------------------------
// Segment descriptors.  A: (M,K) rm bf16.  W: (N,K) rm bf16.  K=512/segment.
// ---------------------------------------------------------------------------
struct SegR { const u16* A; int lda; const u16* W; int ldw; };
struct Seg  { const u16* A; long long Az; int lda; const u16* W; long long Wz; int ldw; };

// ---------------------------------------------------------------------------
// OLD 128x128 core (2-barrier/K-step) -- kept for the final fp32 GEMM only.
// ---------------------------------------------------------------------------
template<int NSEG, int OUTBF>
__device__ __forceinline__ void gemm_core(const SegR* segs,
                                          const float* __restrict__ bias0,
                                          const float* __restrict__ bias1,
                                          void* __restrict__ outp, int ldo)
{
    __shared__ u16 As[128 * 64];
    __shared__ u16 Bs[128 * 64];
    const int tid  = threadIdx.x;
    const int lane = tid & 63;
    const int wv   = tid >> 6;
    const int wm   = wv >> 1, wn = wv & 1;
    const long long rowBase = (long long)blockIdx.y * 128;
    const long long colBase = (long long)blockIdx.x * 128;

    f32x4 acc[4][4];
#pragma unroll
    for (int a = 0; a < 4; ++a)
#pragma unroll
        for (int b = 0; b < 4; ++b) acc[a][b] = (f32x4){0.f, 0.f, 0.f, 0.f};

    const int srow  = tid >> 3;
    const int swcol = (((tid & 7) ^ (srow & 7)) << 3);
    const int dcol  = (tid & 7) << 3;
    const int lrow  = lane & 15;
    const int lquad = lane >> 4;

#pragma unroll
    for (int sg = 0; sg < NSEG; ++sg) {
        const int lda = segs[sg].lda, ldw = segs[sg].ldw;
        const u16* Ab = segs[sg].A + (rowBase + srow) * (long long)lda + swcol;
        const u16* Wb = segs[sg].W + (colBase + srow) * (long long)ldw + swcol;
        for (int kt = 0; kt < 512; kt += 64) {
#pragma unroll
            for (int i = 0; i < 4; ++i) {
                async16(Ab + (long long)(i * 32) * lda + kt, &As[(i * 32 + srow) * 64 + dcol]);
                async16(Wb + (long long)(i * 32) * ldw + kt, &Bs[(i * 32 + srow) * 64 + dcol]);
            }
            __syncthreads();
#pragma unroll
            for (int kk = 0; kk < 64; kk += 32) {
                const int ca = ((((kk >> 3) + lquad) ^ (lrow & 7)) << 3);
                bf16x8 af[4], bw[4];
#pragma unroll
                for (int t = 0; t < 4; ++t)
                    af[t] = *(const bf16x8*)&As[(wm * 64 + t * 16 + lrow) * 64 + ca];
#pragma unroll
                for (int t = 0; t < 4; ++t)
                    bw[t] = *(const bf16x8*)&Bs[(wn * 64 + t * 16 + lrow) * 64 + ca];
#pragma unroll
                for (int mt = 0; mt < 4; ++mt)
#pragma unroll
                    for (int nt = 0; nt < 4; ++nt)
                        acc[mt][nt] = __builtin_amdgcn_mfma_f32_16x16x32_bf16(
                            af[mt], bw[nt], acc[mt][nt], 0, 0, 0);
            }
            __syncthreads();
        }
    }

#pragma unroll
    for (int nt = 0; nt < 4; ++nt) {
        const long long col = colBase + wn * 64 + nt * 16 + lrow;
        float bvv = bias0[col];
        if (bias1) bvv += bias1[col];
#pragma unroll
        for (int mt = 0; mt < 4; ++mt) {
            const long long row0 = rowBase + wm * 64 + mt * 16 + lquad * 4;
#pragma unroll
            for (int r = 0; r < 4; ++r) {
                const float val = acc[mt][nt][r] + bvv;
                const long long o = (row0 + r) * (long long)ldo + col;
                if (OUTBF) ((u16*)outp)[o] = f2bf(val);
                else       ((float*)outp)[o] = val;
            }
        }
    }
}

template<int NSEG, int OUTBF>
__global__ __launch_bounds__(256, 2)
void gemm_seg_kernel(Seg s0, Seg s1, Seg s2, Seg s3,
                     const float* bias0, long long b0z,
                     const float* bias1, long long b1z,
                     void* outp, long long outz, int ldo)
{
    const int z = blockIdx.z;
    const Seg segsIn[4] = {s0, s1, s2, s3};
    SegR segs[NSEG];
#pragma unroll
    for (int i = 0; i < NSEG; ++i) {
        segs[i].A   = segsIn[i].A + (long long)z * segsIn[i].Az;
        segs[i].lda = segsIn[i].lda;
        segs[i].W   = segsIn[i].W + (long long)z * segsIn[i].Wz;
        segs[i].ldw = segsIn[i].ldw;
    }
    gemm_core<NSEG, OUTBF>(segs,
        bias0 + (long long)z * b0z,
        bias1 ? bias1 + (long long)z * b1z : nullptr,
        OUTBF ? (void*)((u16*)outp + (long long)z * outz)
              : (void*)((float*)outp + (long long)z * outz),
        ldo);
}

// ---------------------------------------------------------------------------
// NEW 256x256 deep-pipelined core.  BK=32, ring of 4 LDS slots (32KB each),
// 512 threads = 8 waves (2M x 4N), per-wave output 128x64 (acc 8x4 frags).
//
// Pipeline (iteration t):  STAGE(t+2) -> s_waitcnt vmcnt(8) -> s_barrier
//                          -> ds_read slot[t&3] -> 32 MFMA (setprio 1)
// RAW: each wave's own vmcnt(8) (slots t+1,t+2 in flight) precedes barrier t.
// WAR: slot (t+2)&3 == (t-2)&3; its reads (iter t-2) precede every wave's
//      arrival at barrier t-1, which precedes any wave's STAGE(t+2).
//
// LDS layout per slot: A[0,8192) u16, B[8192,16384) u16.  Logical (row r,
// 16B-chunk k8 of 4) packed into 128B row-pairs with XOR swizzle:
//   o16 = (r>>1)*8 + ((((r&1)<<2)|k8) ^ ((r>>1)&7))
// -> ds_read_b128 hits the 8 words/bank minimum (conflict-free).
// Staging pre-swizzles the GLOBAL source (dest of global_load_lds is linear).
// ---------------------------------------------------------------------------
template<int NSEG>
__device__ __forceinline__ void gemm256_core(const SegR* segs,
                                             const float* __restrict__ bias0,
                                             const float* __restrict__ bias1,
                                             u16* __restrict__ outp, int ldo)
{
    __shared__ u16 lds[4 * 16384];   // 128 KiB: 4 slots x (A 16KB + B 16KB)

    const int tid  = threadIdx.x;            // 0..511
    const int lane = tid & 63;
    const int wv   = tid >> 6;               // 8 waves
    const int wm   = wv >> 2;                // 0..1  (M half)
    const int wn   = wv & 3;                 // 0..3  (N quarter)

    // ---- tile coords with bijective XCD-chunked swizzle (T1) ----
    const int nx  = gridDim.x;
    const int nwg = nx * gridDim.y;
    int lg = blockIdx.y * nx + blockIdx.x;
    if ((nwg & 7) == 0) {
        const int cpx = nwg >> 3;
        lg = (lg & 7) * cpx + (lg >> 3);
    }
    const long long rowBase = (long long)(lg / nx) * 256;
    const long long colBase = (long long)(lg % nx) * 256;

    f32x4 acc[8][4];
#pragma unroll
    for (int i = 0; i < 8; ++i)
#pragma unroll
        for (int j = 0; j < 4; ++j) acc[i][j] = (f32x4){0.f, 0.f, 0.f, 0.f};

    // ---- per-thread static stage decode: LDS chunk o -> global (row, k) ----
    // o = li*512 + tid;  R=o>>3, p=o&7, c=p^(R&7), r=2R+(c>>2), k=(c&3)*8
    const u16* pa0[2]; const u16* pa1[2];
    const u16* pb0[2]; const u16* pb1[2];
#pragma unroll
    for (int li = 0; li < 2; ++li) {
        const int o = li * 512 + tid;
        const int R = o >> 3;
        const int c = (o & 7) ^ (R & 7);
        const int r = 2 * R + (c >> 2);
        const int k = (c & 3) * 8;
        pa0[li] = segs[0].A + (rowBase + r) * (long long)segs[0].lda + k;
        pb0[li] = segs[0].W + (colBase + r) * (long long)segs[0].ldw + k;
        pa1[li] = pa0[li]; pb1[li] = pb0[li];
        if (NSEG > 1) {
            pa1[li] = segs[1].A + (rowBase + r) * (long long)segs[1].lda + k;
            pb1[li] = segs[1].W + (colBase + r) * (long long)segs[1].ldw + k;
        }
    }

    // ---- per-thread static ds_read offsets (u16 units) ----
    int oa[8];
#pragma unroll
    for (int i = 0; i < 8; ++i) {
        const int r = wm * 128 + i * 16 + (lane & 15);
        const int R = r >> 1;
        const int c = (((r & 1) << 2) | (lane >> 4)) ^ (R & 7);
        oa[i] = (R * 8 + c) * 8;
    }
    int ob[4];
#pragma unroll
    for (int j = 0; j < 4; ++j) {
        const int r = wn * 64 + j * 16 + (lane & 15);
        const int R = r >> 1;
        const int c = (((r & 1) << 2) | (lane >> 4)) ^ (R & 7);
        ob[j] = 8192 + (R * 8 + c) * 8;
    }

    auto stage = [&](int slot, int t) {
        const long long kt = (long long)(t & 15) * 32;
        u16* sb = &lds[slot * 16384];
        const bool s1 = (NSEG > 1) && (t >> 4);
#pragma unroll
        for (int li = 0; li < 2; ++li) {
            const u16* ap = s1 ? pa1[li] : pa0[li];
            const u16* bp = s1 ? pb1[li] : pb0[li];
            async16(ap + kt, sb + li * 4096 + tid * 8);
            async16(bp + kt, sb + 8192 + li * 4096 + tid * 8);
        }
    };

    auto compute = [&](int t) {
        const u16* sb = &lds[(t & 3) * 16384];
        bf16x8 af[8], bw[4];
#pragma unroll
        for (int i = 0; i < 8; ++i) af[i] = *(const bf16x8*)(sb + oa[i]);
#pragma unroll
        for (int j = 0; j < 4; ++j) bw[j] = *(const bf16x8*)(sb + ob[j]);
        __builtin_amdgcn_s_setprio(1);
#pragma unroll
        for (int i = 0; i < 8; ++i)
#pragma unroll
            for (int j = 0; j < 4; ++j)
                acc[i][j] = __builtin_amdgcn_mfma_f32_16x16x32_bf16(
                    af[i], bw[j], acc[i][j], 0, 0, 0);
        __builtin_amdgcn_s_setprio(0);
    };

    const int nt = NSEG * 16;        // K-tiles of 32

    stage(0, 0);
    stage(1, 1);
#pragma unroll 1
    for (int t = 0; t < nt - 2; ++t) {
        stage((t + 2) & 3, t + 2);
        asm volatile("s_waitcnt vmcnt(8)" ::: "memory");   // slots t+1,t+2 stay in flight
        __builtin_amdgcn_s_barrier();
        asm volatile("" ::: "memory");
        compute(t);
    }
    asm volatile("s_waitcnt vmcnt(4)" ::: "memory");
    __builtin_amdgcn_s_barrier();
    asm volatile("" ::: "memory");
    compute(nt - 2);
    asm volatile("s_waitcnt vmcnt(0)" ::: "memory");
    __builtin_amdgcn_s_barrier();
    asm volatile("" ::: "memory");
    compute(nt - 1);

    // epilogue: C/D layout col=lane&15, row=(lane>>4)*4+reg  [m89-verified]
    const bool hb1 = (bias1 != nullptr);
#pragma unroll
    for (int j = 0; j < 4; ++j) {
        const long long col = colBase + wn * 64 + j * 16 + (lane & 15);
        float bv = bias0[col];
        if (hb1) bv += bias1[col];
#pragma unroll
        for (int i = 0; i < 8; ++i) {
            const long long row0 = rowBase + wm * 128 + i * 16 + (lane >> 4) * 4;
#pragma unroll
            for (int r = 0; r < 4; ++r)
                outp[(row0 + r) * (long long)ldo + col] = f2bf(acc[i][j][r] + bv);
        }
    }
}

template<int NSEG>
__global__ __launch_bounds__(512, 2)
void gemm256_seg_kernel(Seg s0, Seg s1,
                        const float* bias0, long long b0z,
                        const float* bias1, long long b1z,
                        u16* outp, long long outz, int ldo)
{
    const int z = blockIdx.z;
    SegR segs[2];
    segs[0].A = s0.A + (long long)z * s0.Az; segs[0].lda = s0.lda;
    segs[0].W = s0.W + (long long)z * s0.Wz; segs[0].ldw = s0.ldw;
    segs[1] = segs[0];
    if (NSEG > 1) {
        segs[1].A = s1.A + (long long)z * s1.Az; segs[1].lda = s1.lda;
        segs[1].W = s1.W + (long long)z * s1.Wz; segs[1].ldw = s1.ldw;
    }
    gemm256_core<NSEG>(segs,
        bias0 + (long long)z * b0z,
        bias1 ? bias1 + (long long)z * b1z : nullptr,
        outp + (long long)z * outz, ldo);
}

// q/k/v wrapper: z in [0,7): 0-2 = k[s], 3-5 = v[s], 6 = q.
__global__ __launch_bounds__(512, 2)
void qkv256_kernel(const u16* __restrict__ hnew, const u16* __restrict__ ssm,
                   const u16* __restrict__ inpj, const float* __restrict__ ipb,
                   u16* __restrict__ kout, u16* __restrict__ vout,
                   u16* __restrict__ qout)
{
    const int z = blockIdx.z;
    const long long BD = (long long)Bq * Dq;
    SegR seg[1];
    const float* bias;
    u16* out;
    if (z < 3) {
        seg[0].A = hnew + z * BD;        seg[0].W = inpj + Dq * Dq;
        bias = ipb + Dq;                 out = kout + z * BD;
    } else if (z < 6) {
        seg[0].A = hnew + (z - 3) * BD;  seg[0].W = inpj + 2 * Dq * Dq;
        bias = ipb + 2 * Dq;             out = vout + (z - 3) * BD;
    } else {
        seg[0].A = ssm;                  seg[0].W = inpj;
        bias = ipb;                      out = qout;
    }
    seg[0].lda = Dq; seg[0].ldw = Dq;
    gemm256_core<1>(seg, bias, nullptr, out, Dq);
}

// ---------------------------------------------------------------------------
// LayerNorm + exact GELU, in-place on bf16 xs (S,B,D). One wave per row.
// ---------------------------------------------------------------------------
__global__ __launch_bounds__(256) void ln_gelu_kernel(u16* __restrict__ xs,
                                                      const float* __restrict__ ln_g,
                                                      const float* __restrict__ ln_b)
{
    const int lane = threadIdx.x & 63;
    const int wvi  = threadIdx.x >> 6;
    const long long row = (long long)blockIdx.x * 4 + wvi;
    const int s = (int)(row >> 14);
    u16* p = xs + row * Dq + lane * 8;
    u16x8 u = *(const u16x8*)p;
    float v[8];
    float sum = 0.f, sq = 0.f;
#pragma unroll
    for (int j = 0; j < 8; ++j) { v[j] = bf2f(u[j]); sum += v[j]; sq += v[j] * v[j]; }
#pragma unroll
    for (int m = 32; m >= 1; m >>= 1) { sum += __shfl_xor(sum, m, 64); sq += __shfl_xor(sq, m, 64); }
    const float mu   = sum * (1.f / 512.f);
    const float var  = sq * (1.f / 512.f) - mu * mu;
    const float rstd = rsqrtf(var + 1e-5f);
    const float* g = ln_g + (size_t)s * Dq + lane * 8;
    const float* b = ln_b + (size_t)s * Dq + lane * 8;
    u16x8 o;
#pragma unroll
    for (int j = 0; j < 8; ++j) {
        float y  = (v[j] - mu) * rstd * g[j] + b[j];
        float ge = 0.5f * y * (1.f + erff(y * 0.70710678118654752f));
        o[j] = f2bf(ge);
    }
    *(u16x8*)p = o;
}

// ---------------------------------------------------------------------------
// LSTM pointwise, all S in one launch, 8 elem/thread, fast sig/tanh.
// ---------------------------------------------------------------------------
__global__ __launch_bounds__(256) void lstm_kernel(const u16* __restrict__ gates_all,
                                                   const float* __restrict__ cprev,
                                                   const float* __restrict__ decays,
                                                   float* __restrict__ hout,
                                                   float* __restrict__ cout,
                                                   u16* __restrict__ hbf)
{
    const long long i = ((long long)blockIdx.x * 256 + threadIdx.x) * 8;  // over S*B*D
    const int s = (int)(i >> 23);                 // BD = 2^23
    const long long off = i & ((1LL << 23) - 1);
    const long long bi = off >> 9;
    const int d = (int)(off & 511);
    const u16* g = gates_all + ((long long)s << 25) + bi * 2048 + d;
    u16x8 ig = *(const u16x8*)(g);
    u16x8 fg = *(const u16x8*)(g + 512);
    u16x8 gg = *(const u16x8*)(g + 1024);
    u16x8 og = *(const u16x8*)(g + 1536);
    float4 cp0 = *(const float4*)(cprev + i);
    float4 cp1 = *(const float4*)(cprev + i + 4);
    float cpa[8] = {cp0.x, cp0.y, cp0.z, cp0.w, cp1.x, cp1.y, cp1.z, cp1.w};
    const float dec = decays[s];
    float hv[8], cv[8]; u16x8 hb;
#pragma unroll
    for (int j = 0; j < 8; ++j) {
        float igf = sigf(bf2f(ig[j]));
        float fgf = sigf(bf2f(fg[j]));
        float ggf = tanhfast(bf2f(gg[j]));
        float ogf = sigf(bf2f(og[j]));
        float cl  = fgf * cpa[j] + igf * ggf;
        float hn  = ogf * tanhfast(cl);
        hv[j] = hn;
        cv[j] = dec * cpa[j] + (1.f - dec) * cl;
        hb[j] = f2bf(hn);
    }
    *(float4*)(hout + i)     = make_float4(hv[0], hv[1], hv[2], hv[3]);
    *(float4*)(hout + i + 4) = make_float4(hv[4], hv[5], hv[6], hv[7]);
    *(float4*)(cout + i)     = make_float4(cv[0], cv[1], cv[2], cv[3]);
    *(float4*)(cout + i + 4) = make_float4(cv[4], cv[5], cv[6], cv[7]);
    *(u16x8*)(hbf + i)       = hb;
}

// ---------------------------------------------------------------------------
// Attention over S=3. One wave per (b,h); lane = head-dim element.
// ---------------------------------------------------------------------------
__global__ __launch_bounds__(256) void attn_kernel(const u16* __restrict__ q,
                                                   const u16* __restrict__ k,
                                                   const u16* __restrict__ v,
                                                   u16* __restrict__ fused)
{
    const int lane = threadIdx.x & 63;
    const int wvi  = threadIdx.x >> 6;
    const long long idx = (long long)blockIdx.x * 4 + wvi;
    const long long off = idx * 64 + lane;
    const float qv = bf2f(q[off]);
    float sc[3];
#pragma unroll
    for (int s = 0; s < 3; ++s) {
        float p = qv * bf2f(k[(long long)s * Bq * Dq + off]);
#pragma unroll
        for (int m = 32; m >= 1; m >>= 1) p += __shfl_xor(p, m, 64);
        sc[s] = p * 0.125f;
    }
    const float mx = fmaxf(sc[0], fmaxf(sc[1], sc[2]));
    const float e0 = expf(sc[0] - mx), e1 = expf(sc[1] - mx), e2 = expf(sc[2] - mx);
    const float inv = 1.f / (e0 + e1 + e2);
    const float f = (e0 * bf2f(v[off]) +
                     e1 * bf2f(v[(long long)Bq * Dq + off]) +
                     e2 * bf2f(v[2LL * Bq * Dq + off])) * inv;
    fused[off] = f2bf(f);
}

// ---------------------------------------------------------------------------
// Host launcher
// ---------------------------------------------------------------------------
extern "C" void kernel_launch(void* const* d_in, const int* in_sizes, int n_in,
                              void* d_out, int out_size, void* d_ws, size_t ws_size,
                              hipStream_t stream)
{
    (void)in_sizes; (void)n_in; (void)out_size; (void)ws_size;

    const float* x         = (const float*)d_in[0];
    const float* h_prev    = (const float*)d_in[1];
    const float* c_prev    = (const float*)d_in[2];
    const float* ssm       = (const float*)d_in[3];
    const float* Wt        = (const float*)d_in[4];
    const float* bt        = (const float*)d_in[5];
    const float* ln_g      = (const float*)d_in[6];
    const float* ln_b      = (const float*)d_in[7];
    const float* W_ih      = (const float*)d_in[8];
    const float* W_hh      = (const float*)d_in[9];
    const float* b_ih      = (const float*)d_in[10];
    const float* b_hh      = (const float*)d_in[11];
    const float* decays    = (const float*)d_in[12];
    const float* in_proj_w = (const float*)d_in[13];
    const float* in_proj_b = (const float*)d_in[14];
    const float* out_proj_w= (const float*)d_in[15];
    const float* out_proj_b= (const float*)d_in[16];
    const float* mix_w     = (const float*)d_in[17];
    const float* mix_b     = (const float*)d_in[18];
    float* out = (float*)d_out;

    const long long BD = (long long)Bq * Dq;

    // ---- workspace layout (bf16 elements) ----
    u16* base = (u16*)d_ws;
    size_t off = 0;
    auto walloc = [&](size_t n) { u16* p = base + off; off += (n + 4095) & ~(size_t)4095; return p; };
    u16* wt_bf    = walloc((size_t)Sq * Dq * Dq);
    u16* wih_bf   = walloc((size_t)Sq * 4 * Dq * Dq);
    u16* whh_bf   = walloc((size_t)Sq * 4 * Dq * Dq);
    u16* inpj_bf  = walloc((size_t)3 * Dq * Dq);
    u16* outpj_bf = walloc((size_t)Dq * Dq);
    u16* mix_bf   = walloc((size_t)Dq * Sq * Dq);
    u16* x_bf     = walloc((size_t)Bq * Dq);
    u16* ssm_bf   = walloc((size_t)Bq * Dq);
    u16* hprev_bf = walloc((size_t)Sq * Bq * Dq);
    u16* xs_bf    = walloc((size_t)Sq * Bq * Dq);
    u16* gates_bf = walloc((size_t)Sq * Bq * 4 * Dq);
    u16* hnew_bf  = walloc((size_t)Sq * Bq * Dq);
    u16* k_bf  = xs_bf;                     // xs dead after gates GEMM
    u16* v_bf  = hprev_bf;                  // h_prev dead after gates GEMM
    u16* q_bf  = gates_bf;                  // gates dead after LSTM
    u16* fu_bf = gates_bf + BD;

    // ---- one fused convert launch ----
    {
        CvtArgs a;
        const float* srcs[9] = {x, ssm, h_prev, Wt, W_ih, W_hh, in_proj_w, out_proj_w, mix_w};
        u16* dsts[9] = {x_bf, ssm_bf, hprev_bf, wt_bf, wih_bf, whh_bf, inpj_bf, outpj_bf, mix_bf};
        const long long ns[9] = {BD, BD, Sq * BD,
                                 (long long)Sq * Dq * Dq, (long long)Sq * 4 * Dq * Dq,
                                 (long long)Sq * 4 * Dq * Dq, (long long)3 * Dq * Dq,
                                 (long long)Dq * Dq, (long long)Dq * Sq * Dq};
        long long acc = 0;
        for (int i = 0; i < 9; ++i) { a.src[i] = srcs[i]; a.dst[i] = dsts[i]; acc += ns[i]; a.bound[i] = acc; }
        cvt_all_kernel<<<dim3((unsigned)((acc / 8 + 255) / 256)), 256, 0, stream>>>(a, acc);
    }

    Seg zs{nullptr, 0, 0, nullptr, 0, 0};

    // xs[s] = x @ Wt[s]^T + bt[s]     (z over S)  [256^2 core]
    {
        Seg a{x_bf, 0, Dq, wt_bf, (long long)Dq * Dq, Dq};
        gemm256_seg_kernel<1><<<dim3(Dq / 256, Bq / 256, Sq), 512, 0, stream>>>(
            a, zs, bt, Dq, nullptr, 0, xs_bf, BD, Dq);
    }
    ln_gelu_kernel<<<dim3(Sq * Bq / 4), 256, 0, stream>>>(xs_bf, ln_g, ln_b);

    // gates[s] = xs[s]@W_ih[s]^T + h_prev[s]@W_hh[s]^T + biases  (z over S)
    {
        Seg a{xs_bf, BD, Dq, wih_bf, (long long)4 * Dq * Dq, Dq};
        Seg b{hprev_bf, BD, Dq, whh_bf, (long long)4 * Dq * Dq, Dq};
        gemm256_seg_kernel<2><<<dim3(4 * Dq / 256, Bq / 256, Sq), 512, 0, stream>>>(
            a, b, b_ih, 4 * Dq, b_hh, 4 * Dq, gates_bf, 4 * BD, 4 * Dq);
    }
    // LSTM pointwise, all S
    lstm_kernel<<<dim3((unsigned)(Sq * BD / 2048)), 256, 0, stream>>>(
        gates_bf, c_prev, decays,
        out + BD,                 // h_new slot
        out + 4 * BD,             // c_new slot
        hnew_bf);

    // q/k/v in one launch (z=7)  [256^2 core]
    qkv256_kernel<<<dim3(Dq / 256, Bq / 256, 7), 512, 0, stream>>>(
        hnew_bf, ssm_bf, inpj_bf, in_proj_b, k_bf, v_bf, q_bf);

    attn_kernel<<<dim3(Bq * Hq / 4), 256, 0, stream>>>(q_bf, k_bf, v_bf, fu_bf);

    // out = sum_s h_new[s] @ mix_w[:, s*D:(s+1)*D]^T + fused @ out_proj^T
    //       + mix_b + out_proj_b          (old 128^2 core, fp32 out)
    {
        Seg a0{hnew_bf, 0, Dq, mix_bf, 0, Sq * Dq};
        Seg a1{hnew_bf + BD, 0, Dq, mix_bf + Dq, 0, Sq * Dq};
        Seg a2{hnew_bf + 2 * BD, 0, Dq, mix_bf + 2 * Dq, 0, Sq * Dq};
        Seg a3{fu_bf, 0, Dq, outpj_bf, 0, Dq};
        gemm_seg_kernel<4, 0><<<dim3(Dq / 128, Bq / 128, 1), 256, 0, stream>>>(
            a0, a1, a2, a3, mix_b, 0, out_proj_b, 0, out, 0, Dq);
    }
}